// Round 2
// 3767.707 us; speedup vs baseline: 1.6365x; 1.6365x over previous
//
#include <hip/hip_runtime.h>
#include <math.h>

typedef __attribute__((ext_vector_type(8))) short short8;
typedef __attribute__((ext_vector_type(8))) _Float16 half8;
typedef __attribute__((ext_vector_type(4))) float f32x4;

static constexpr int Lc = 12;
static constexpr int Hc = 12;
static constexpr int Dc = 768;
static constexpr int DHc = 64;
static constexpr int FFc = 3072;
static constexpr int SENSEc = 64;
static constexpr int ATTc = 64;
static constexpr int QS = 3 * Dc;   // 2304 packed q|k|v
static constexpr int KPAD = 72;     // LDS row stride (shorts) for V^T / P buffers

// fp32 -> fp16 (RNE) bit pattern
__device__ __forceinline__ unsigned short f2h(float f) {
    _Float16 h = (_Float16)f;
    union { _Float16 h; unsigned short u; } c;
    c.h = h;
    return c.u;
}

__device__ __forceinline__ void load_lds16(const void* g, void* l) {
    __builtin_amdgcn_global_load_lds(
        (const __attribute__((address_space(1))) unsigned int*)g,
        (__attribute__((address_space(3))) unsigned int*)l, 16, 0, 0);
}

// ---------------- block reduction (256 threads = 4 waves) ----------------
__device__ __forceinline__ float blockReduceSum256(float v, float* sred) {
#pragma unroll
    for (int off = 32; off > 0; off >>= 1) v += __shfl_down(v, off, 64);
    int lane = threadIdx.x & 63, wid = threadIdx.x >> 6;
    if (lane == 0) sred[wid] = v;
    __syncthreads();
    float total = sred[0] + sred[1] + sred[2] + sred[3];
    __syncthreads();
    return total;
}

// ---------------- embedding + LayerNorm -> x fp32 + fp16 plane ------------
__global__ __launch_bounds__(256) void embed_kernel(
    const int* __restrict__ ids, const int* __restrict__ tts,
    const float* __restrict__ we, const float* __restrict__ pe,
    const float* __restrict__ te, const float* __restrict__ g,
    const float* __restrict__ b, float* __restrict__ x,
    unsigned short* __restrict__ xh, int S)
{
    int tok = blockIdx.x, t = threadIdx.x;
    int ss = tok % S;
    int id = ids[tok], tt = tts[tok];
    __shared__ float sred[4];
    float v[3];
    float s = 0.f;
#pragma unroll
    for (int i = 0; i < 3; ++i) {
        int d = t + i * 256;
        v[i] = we[(size_t)id * Dc + d] + pe[(size_t)ss * Dc + d] + te[(size_t)tt * Dc + d];
        s += v[i];
    }
    float mu = blockReduceSum256(s, sred) * (1.f / Dc);
    float s2 = 0.f;
#pragma unroll
    for (int i = 0; i < 3; ++i) { v[i] -= mu; s2 += v[i] * v[i]; }
    float rstd = rsqrtf(blockReduceSum256(s2, sred) * (1.f / Dc) + 1e-12f);
    size_t ro = (size_t)tok * Dc;
#pragma unroll
    for (int i = 0; i < 3; ++i) {
        int d = t + i * 256;
        float val = v[i] * rstd * g[d] + b[d];
        x[ro + d] = val;
        xh[ro + d] = f2h(val);
    }
}

// ---------------- residual + LayerNorm (in-place x) + fp16 plane ----------------
__global__ __launch_bounds__(256) void resln_kernel(
    float* __restrict__ x, const float* __restrict__ y,
    const float* __restrict__ g, const float* __restrict__ b,
    unsigned short* __restrict__ xh)
{
    int tok = blockIdx.x, t = threadIdx.x;
    __shared__ float sred[4];
    size_t ro = (size_t)tok * Dc;
    float v[3];
    float s = 0.f;
#pragma unroll
    for (int i = 0; i < 3; ++i) {
        int d = t + i * 256;
        v[i] = x[ro + d] + y[ro + d];
        s += v[i];
    }
    float mu = blockReduceSum256(s, sred) * (1.f / Dc);
    float s2 = 0.f;
#pragma unroll
    for (int i = 0; i < 3; ++i) { v[i] -= mu; s2 += v[i] * v[i]; }
    float rstd = rsqrtf(blockReduceSum256(s2, sred) * (1.f / Dc) + 1e-12f);
#pragma unroll
    for (int i = 0; i < 3; ++i) {
        int d = t + i * 256;
        float val = v[i] * rstd * g[d] + b[d];
        x[ro + d] = val;
        xh[ro + d] = f2h(val);
    }
}

// ------------- weight convert+transpose fp32 [K,N] -> fp16 [N,K] -----
__global__ __launch_bounds__(256) void convert_weights(
    const float* __restrict__ Wq, const float* __restrict__ Wk,
    const float* __restrict__ Wv, const float* __restrict__ Wo,
    const float* __restrict__ W1, const float* __restrict__ W2,
    unsigned short* __restrict__ qh, unsigned short* __restrict__ oh,
    unsigned short* __restrict__ h1, unsigned short* __restrict__ h2)
{
    int id = blockIdx.x;
    const float* src; unsigned short *dh; int Kd, Nd, tx, ty;
    if (id < 576) {
        int m = id / 144, tile = id % 144;
        src = (m == 0) ? Wq : (m == 1) ? Wk : (m == 2) ? Wv : Wo;
        if (m < 3) { dh = qh + (size_t)m * Dc * Dc; }
        else       { dh = oh; }
        Kd = Dc; Nd = Dc; tx = tile % 12; ty = tile / 12;
    } else if (id < 1152) {
        int tile = id - 576;
        src = W1; dh = h1; Kd = Dc; Nd = FFc; tx = tile % 48; ty = tile / 48;
    } else {
        int tile = id - 1152;
        src = W2; dh = h2; Kd = FFc; Nd = Dc; tx = tile % 12; ty = tile / 12;
    }
    int k0 = ty * 64, n0 = tx * 64;
    __shared__ float tileS[64][65];
    int t = threadIdx.x, c = t & 63, r0 = t >> 6;
#pragma unroll
    for (int i = 0; i < 16; ++i) {
        int kr = r0 + i * 4;
        tileS[kr][c] = src[(size_t)(k0 + kr) * Nd + n0 + c];
    }
    __syncthreads();
#pragma unroll
    for (int i = 0; i < 16; ++i) {
        int nr = r0 + i * 4;
        float v = tileS[c][nr];
        size_t idx = (size_t)(n0 + nr) * Kd + k0 + c;
        dh[idx] = f2h(v);
    }
}

// ---------------- packed qkv bias [L][2304] ----------------
__global__ __launch_bounds__(256) void biascat_kernel(
    const float* __restrict__ bq, const float* __restrict__ bk,
    const float* __restrict__ bv, float* __restrict__ out)
{
    int lyr = blockIdx.x, t = threadIdx.x;
    for (int j = t; j < QS; j += 256) {
        float v = (j < Dc) ? bq[lyr * Dc + j]
                : (j < 2 * Dc) ? bk[lyr * Dc + j - Dc]
                : bv[lyr * Dc + j - 2 * Dc];
        out[lyr * QS + j] = v;
    }
}

// ------------- fp16 MFMA GEMM: C = A @ Bt^T + bias -------------------------
// LDS planes use a 16B-chunk XOR swizzle: chunk c of row r stored at slot c^(r&7)
// (source-column permutation at staging; fragment reads XOR by row&7). Breaks the
// 128B-row-stride 16-way bank conflict down to free 2-way.
// MODE 0: fp32 out. MODE 1: GELU + fp16 out. MODE 2: fp16 out.
template <int MODE>
__global__ __launch_bounds__(256, 3) void mfma_gemm_f16(
    const unsigned short* __restrict__ Ah, const unsigned short* __restrict__ Bh,
    const float* __restrict__ bias, float* __restrict__ Cf,
    unsigned short* __restrict__ Ch, int M, int N, int K)
{
    __shared__ alignas(16) unsigned short Ash[128 * 64];
    __shared__ alignas(16) unsigned short Bsh[128 * 64];
    int t = threadIdx.x, w = t >> 6, l = t & 63;
    int m0 = blockIdx.y * 128, n0 = blockIdx.x * 128;
    int wm = (w >> 1) * 64, wn = (w & 1) * 64;
    // swizzled source column: this lane's LDS slot (l&7) holds global chunk (l&7)^(row&7)
    int sw = (((l & 7) ^ (l >> 3)) << 3);
    size_t go = (size_t)(w * 8 + (l >> 3)) * K + sw;
    const unsigned short* gah = Ah + (size_t)m0 * K + go;
    const unsigned short* gbh = Bh + (size_t)n0 * K + go;
    int lo = w * 512 + l * 8;
    f32x4 acc[4][4];
#pragma unroll
    for (int i = 0; i < 4; ++i)
#pragma unroll
        for (int j = 0; j < 4; ++j) acc[i][j] = (f32x4)0.f;
    int fm = l & 15, grp = l >> 4;
    int axor = fm & 7;  // row&7 for fragment rows (wm/wn,i*16 are 0 mod 8)
    for (int k0 = 0; k0 < K; k0 += 64) {
        __syncthreads();
#pragma unroll
        for (int i = 0; i < 4; ++i) {
            size_t g = (size_t)(i * 32) * K + k0;
            int d = lo + i * 2048;
            load_lds16(gah + g, Ash + d);
            load_lds16(gbh + g, Bsh + d);
        }
        __syncthreads();
#pragma unroll
        for (int h = 0; h < 2; ++h) {
            int koff = (((h * 4 + grp) ^ axor) << 3);
            half8 fa[4], fb[4];
#pragma unroll
            for (int i = 0; i < 4; ++i) {
                int ra = (wm + i * 16 + fm) * 64 + koff;
                int rb = (wn + i * 16 + fm) * 64 + koff;
                fa[i] = *(const half8*)(Ash + ra);
                fb[i] = *(const half8*)(Bsh + rb);
            }
#pragma unroll
            for (int i = 0; i < 4; ++i)
#pragma unroll
                for (int j = 0; j < 4; ++j)
                    acc[i][j] = __builtin_amdgcn_mfma_f32_16x16x32_f16(
                        fa[i], fb[j], acc[i][j], 0, 0, 0);
        }
    }
    int col_l = l & 15, row_l = (l >> 4) * 4;
#pragma unroll
    for (int j = 0; j < 4; ++j) {
        int col = n0 + wn + j * 16 + col_l;
        float bcv = bias[col];
#pragma unroll
        for (int i = 0; i < 4; ++i) {
            int row = m0 + wm + i * 16 + row_l;
#pragma unroll
            for (int r = 0; r < 4; ++r) {
                float v = acc[i][j][r] + bcv;
                size_t idx = (size_t)(row + r) * N + col;
                if (MODE == 1) {
                    v = 0.5f * v * (1.f + erff(v * 0.70710678118654752f));
                    Ch[idx] = f2h(v);
                } else if (MODE == 2) {
                    Ch[idx] = f2h(v);
                } else {
                    Cf[idx] = v;
                }
            }
        }
    }
}

// ------------- MFMA flash attention: one block per (b,head), 4 waves ------------
// qkv is fp16 [tok][2304] (q|k|v). K staged with the same XOR swizzle (row stride
// 64 shorts); V^T and P use KPAD=72 rows (2-way worst = free). fp32 softmax/O.
__global__ __launch_bounds__(256, 1) void attn_mfma(
    const unsigned short* __restrict__ qkv, const int* __restrict__ mask,
    unsigned short* __restrict__ aoh, int B, int S)
{
    int bh = blockIdx.x, b = bh / Hc, hd = bh % Hc;
    int t = threadIdx.x, w = t >> 6, l = t & 63;
    int grp = l >> 4, lc = l & 15;
    __shared__ alignas(16) unsigned short Ks[256 * 64];       // [key][d] swizzled
    __shared__ alignas(16) unsigned short Vts[4][64 * KPAD];  // [chunk][d][key%64]
    __shared__ alignas(16) unsigned short Pw[4][64 * KPAD];   // [wave][q%64][key%64]
    __shared__ float mb[256];
    size_t rowbase = (size_t)(b * S) * QS;

    mb[t] = (1.f - (float)mask[b * S + t]) * -10000.0f;

    // ---- stage K (swizzled) and V^T panels (fp16 direct) ----
    for (int p = 0; p < 4; ++p) {
        int key = p * 64 + (t >> 2);
        int d0 = (t & 3) * 16;
        const unsigned short* ksrc = qkv + rowbase + (size_t)key * QS + Dc + hd * DHc + d0;
        short8 s0 = *(const short8*)ksrc;
        short8 s1 = *(const short8*)(ksrc + 8);
        int c0 = d0 >> 3;
        *(short8*)(Ks + key * 64 + (((c0 + 0) ^ (key & 7)) << 3)) = s0;
        *(short8*)(Ks + key * 64 + (((c0 + 1) ^ (key & 7)) << 3)) = s1;
        const unsigned short* vsrc = qkv + rowbase + (size_t)key * QS + 2 * Dc + hd * DHc + d0;
        short8 v0 = *(const short8*)vsrc;
        short8 v1 = *(const short8*)(vsrc + 8);
        int kk = t >> 2;
#pragma unroll
        for (int u = 0; u < 8; ++u) {
            Vts[p][(d0 + u) * KPAD + kk]     = (unsigned short)v0[u];
            Vts[p][(d0 + 8 + u) * KPAD + kk] = (unsigned short)v1[u];
        }
    }

    // ---- Q fragments direct from fp16 qkv (A-layout: m=lc, k=grp*8+j) ----
    int q0 = w * 64;
    half8 qf[4][2];
#pragma unroll
    for (int i = 0; i < 4; ++i)
#pragma unroll
        for (int kc = 0; kc < 2; ++kc)
            qf[i][kc] = *(const half8*)(qkv + rowbase
                        + (size_t)(q0 + 16 * i + lc) * QS + hd * DHc + kc * 32 + grp * 8);
    __syncthreads();

    f32x4 oacc[4][4];
#pragma unroll
    for (int i = 0; i < 4; ++i)
#pragma unroll
        for (int j = 0; j < 4; ++j) oacc[i][j] = (f32x4)0.f;
    float mstate[4][4], lstate[4][4];
#pragma unroll
    for (int i = 0; i < 4; ++i)
#pragma unroll
        for (int r = 0; r < 4; ++r) { mstate[i][r] = -3.0e38f; lstate[i][r] = 0.f; }

    for (int c = 0; c < 4; ++c) {
        f32x4 sacc[4][4];
#pragma unroll
        for (int i = 0; i < 4; ++i)
#pragma unroll
            for (int j = 0; j < 4; ++j) sacc[i][j] = (f32x4)0.f;
#pragma unroll
        for (int kc = 0; kc < 2; ++kc) {
            half8 kf[4];
#pragma unroll
            for (int j = 0; j < 4; ++j) {
                int krow = c * 64 + 16 * j + lc;
                kf[j] = *(const half8*)(Ks + krow * 64 + (((kc * 4 + grp) ^ (lc & 7)) << 3));
            }
#pragma unroll
            for (int i = 0; i < 4; ++i)
#pragma unroll
                for (int j = 0; j < 4; ++j)
                    sacc[i][j] = __builtin_amdgcn_mfma_f32_16x16x32_f16(
                        qf[i][kc], kf[j], sacc[i][j], 0, 0, 0);
        }
#pragma unroll
        for (int j = 0; j < 4; ++j) {
            float mbv = mb[c * 64 + 16 * j + lc];
#pragma unroll
            for (int i = 0; i < 4; ++i)
#pragma unroll
                for (int r = 0; r < 4; ++r)
                    sacc[i][j][r] = sacc[i][j][r] * 0.125f + mbv;
        }
#pragma unroll
        for (int i = 0; i < 4; ++i)
#pragma unroll
            for (int r = 0; r < 4; ++r) {
                float cm = fmaxf(fmaxf(sacc[i][0][r], sacc[i][1][r]),
                                 fmaxf(sacc[i][2][r], sacc[i][3][r]));
#pragma unroll
                for (int mw = 1; mw < 16; mw <<= 1)
                    cm = fmaxf(cm, __shfl_xor(cm, mw, 16));
                float nm = fmaxf(mstate[i][r], cm);
                float alpha = expf(mstate[i][r] - nm);
                mstate[i][r] = nm;
                float rs = 0.f;
#pragma unroll
                for (int j = 0; j < 4; ++j) {
                    float p = expf(sacc[i][j][r] - nm);
                    sacc[i][j][r] = p;
                    rs += p;
                }
#pragma unroll
                for (int mw = 1; mw < 16; mw <<= 1)
                    rs += __shfl_xor(rs, mw, 16);
                lstate[i][r] = lstate[i][r] * alpha + rs;
#pragma unroll
                for (int j = 0; j < 4; ++j) oacc[i][j][r] *= alpha;
            }
#pragma unroll
        for (int i = 0; i < 4; ++i)
#pragma unroll
            for (int j = 0; j < 4; ++j)
#pragma unroll
                for (int r = 0; r < 4; ++r)
                    Pw[w][(16 * i + 4 * grp + r) * KPAD + 16 * j + lc] =
                        f2h(sacc[i][j][r]);
        __syncthreads();
#pragma unroll
        for (int kc = 0; kc < 2; ++kc) {
            half8 pf[4], vf[4];
#pragma unroll
            for (int i = 0; i < 4; ++i)
                pf[i] = *(const half8*)(&Pw[w][(16 * i + lc) * KPAD + kc * 32 + grp * 8]);
#pragma unroll
            for (int j = 0; j < 4; ++j)
                vf[j] = *(const half8*)(&Vts[c][(16 * j + lc) * KPAD + kc * 32 + grp * 8]);
#pragma unroll
            for (int i = 0; i < 4; ++i)
#pragma unroll
                for (int j = 0; j < 4; ++j)
                    oacc[i][j] = __builtin_amdgcn_mfma_f32_16x16x32_f16(
                        pf[i], vf[j], oacc[i][j], 0, 0, 0);
        }
        __syncthreads();
    }
#pragma unroll
    for (int i = 0; i < 4; ++i)
#pragma unroll
        for (int r = 0; r < 4; ++r) {
            float inv = 1.f / lstate[i][r];
            size_t tok = (size_t)(b * S + q0 + 16 * i + 4 * grp + r);
#pragma unroll
            for (int j = 0; j < 4; ++j) {
                float v = oacc[i][j][r] * inv;
                size_t idx = tok * Dc + hd * DHc + 16 * j + lc;
                aoh[idx] = f2h(v);
            }
        }
}

// ---------------- final head (fp32 from fp32 master) ----------------
__global__ __launch_bounds__(64) void pun_proj_kernel(
    const float* __restrict__ x, const int* __restrict__ loc,
    const float* __restrict__ Wq, float* __restrict__ pq, int S)
{
    __shared__ float pun[Dc];
    int b = blockIdx.x, t = threadIdx.x;
    const float* row = x + ((size_t)b * S + loc[b]) * Dc;
    for (int i = t; i < Dc; i += 64) pun[i] = row[i];
    __syncthreads();
    float acc = 0.f;
    for (int d = 0; d < Dc; ++d) acc += pun[d] * Wq[(size_t)d * ATTc + t];
    pq[b * ATTc + t] = acc;
}

__global__ __launch_bounds__(64) void sense_proj_kernel(
    const float* __restrict__ se, const float* __restrict__ Wk,
    float* __restrict__ sk)
{
    __shared__ float srow[Dc];
    int i = blockIdx.x, t = threadIdx.x;
    const float* row = se + (size_t)i * Dc;
    for (int j = t; j < Dc; j += 64) srow[j] = row[j];
    __syncthreads();
    float acc = 0.f;
    for (int d = 0; d < Dc; ++d) acc += srow[d] * Wk[(size_t)d * ATTc + t];
    sk[i * ATTc + t] = acc;
}

__global__ __launch_bounds__(64) void top2_kernel(
    const float* __restrict__ pq, const float* __restrict__ sk,
    float* __restrict__ out)
{
    __shared__ float pqs[ATTc];
    __shared__ float scs[SENSEc];
    int b = blockIdx.x, t = threadIdx.x;
    pqs[t] = pq[b * ATTc + t];
    __syncthreads();
    float acc = 0.f;
#pragma unroll
    for (int d = 0; d < ATTc; ++d) acc += pqs[d] * sk[t * ATTc + d];
    scs[t] = acc;
    __syncthreads();
    if (t == 0) {
        float v1 = -INFINITY, v2 = -INFINITY;
        int i1 = 0, i2 = 0;
        for (int i = 0; i < SENSEc; ++i) {
            float s = scs[i];
            if (s > v1) { v2 = v1; i2 = i1; v1 = s; i1 = i; }
            else if (s > v2) { v2 = s; i2 = i; }
        }
        out[b * 2 + 0] = (float)i1;
        out[b * 2 + 1] = (float)i2;
    }
}

extern "C" void kernel_launch(void* const* d_in, const int* in_sizes, int n_in,
                              void* d_out, int out_size, void* d_ws, size_t ws_size,
                              hipStream_t stream)
{
    (void)n_in; (void)out_size; (void)ws_size;
    const int*   input_ids  = (const int*)d_in[0];
    const int*   token_type = (const int*)d_in[1];
    const int*   attn_mask  = (const int*)d_in[2];
    const int*   location   = (const int*)d_in[3];
    const float* sense_emb  = (const float*)d_in[4];
    const float* word_emb   = (const float*)d_in[5];
    const float* pos_emb    = (const float*)d_in[6];
    const float* type_emb   = (const float*)d_in[7];
    const float* eg         = (const float*)d_in[8];
    const float* eb         = (const float*)d_in[9];
    const float* Wq         = (const float*)d_in[10];
    const float* bq         = (const float*)d_in[11];
    const float* Wk         = (const float*)d_in[12];
    const float* bk         = (const float*)d_in[13];
    const float* Wv         = (const float*)d_in[14];
    const float* bv         = (const float*)d_in[15];
    const float* Wo         = (const float*)d_in[16];
    const float* bo         = (const float*)d_in[17];
    const float* ln1g       = (const float*)d_in[18];
    const float* ln1b       = (const float*)d_in[19];
    const float* W1         = (const float*)d_in[20];
    const float* b1         = (const float*)d_in[21];
    const float* W2         = (const float*)d_in[22];
    const float* b2         = (const float*)d_in[23];
    const float* ln2g       = (const float*)d_in[24];
    const float* ln2b       = (const float*)d_in[25];
    const float* attWq      = (const float*)d_in[26];
    const float* attWk      = (const float*)d_in[27];
    float* out = (float*)d_out;

    int B = in_sizes[3];      // 32
    int S = in_sizes[0] / B;  // 256
    int NT = B * S;           // 8192
    size_t NTD = (size_t)NT * Dc;

    float*          x   = (float*)d_ws;
    unsigned short* xh  = (unsigned short*)(x + NTD);
    float*          y   = (float*)(xh + NTD);
    // scratch union (sized by hh = [NT,FF] fp16): {qkv fp16 + aoh} <-> {hh}
    unsigned short* hh  = (unsigned short*)(y + NTD);   // [NT,FF]
    unsigned short* qkv = hh;                           // [NT,2304] fp16 (aliases hh)
    unsigned short* aoh = qkv + (size_t)NT * QS;        // [NT,D]
    float*          bc  = (float*)(hh + (size_t)NT * FFc);  // [L,2304]
    unsigned short* wqh = (unsigned short*)(bc + (size_t)Lc * QS);
    unsigned short* woh = wqh + (size_t)QS * Dc;
    unsigned short* w1h = woh + (size_t)Dc * Dc;
    unsigned short* w2h = w1h + (size_t)FFc * Dc;
    float*          pq  = (float*)(w2h + (size_t)Dc * FFc);
    float*          sk  = pq + (size_t)B * ATTc;

    embed_kernel<<<NT, 256, 0, stream>>>(input_ids, token_type, word_emb,
                                         pos_emb, type_emb, eg, eb, x, xh, S);
    biascat_kernel<<<Lc, 256, 0, stream>>>(bq, bk, bv, bc);

    dim3 gQKV(QS / 128, NT / 128);
    dim3 gD(Dc / 128, NT / 128);
    dim3 gF(FFc / 128, NT / 128);
    for (int l = 0; l < Lc; ++l) {
        convert_weights<<<1728, 256, 0, stream>>>(
            Wq + (size_t)l * Dc * Dc, Wk + (size_t)l * Dc * Dc,
            Wv + (size_t)l * Dc * Dc, Wo + (size_t)l * Dc * Dc,
            W1 + (size_t)l * Dc * FFc, W2 + (size_t)l * FFc * Dc,
            wqh, woh, w1h, w2h);
        mfma_gemm_f16<2><<<gQKV, 256, 0, stream>>>(
            xh, wqh, bc + (size_t)l * QS, nullptr, qkv, NT, QS, Dc);
        attn_mfma<<<B * Hc, 256, 0, stream>>>(qkv, attn_mask, aoh, B, S);
        mfma_gemm_f16<0><<<gD, 256, 0, stream>>>(
            aoh, woh, bo + (size_t)l * Dc, y, nullptr, NT, Dc, Dc);
        resln_kernel<<<NT, 256, 0, stream>>>(x, y, ln1g + (size_t)l * Dc,
                                             ln1b + (size_t)l * Dc, xh);
        mfma_gemm_f16<1><<<gF, 256, 0, stream>>>(
            xh, w1h, b1 + (size_t)l * FFc, nullptr, hh, NT, FFc, Dc);
        mfma_gemm_f16<0><<<gD, 256, 0, stream>>>(
            hh, w2h, b2 + (size_t)l * Dc, y, nullptr, NT, Dc, FFc);
        resln_kernel<<<NT, 256, 0, stream>>>(x, y, ln2g + (size_t)l * Dc,
                                             ln2b + (size_t)l * Dc, xh);
    }

    pun_proj_kernel<<<B, 64, 0, stream>>>(x, location, attWq, pq, S);
    sense_proj_kernel<<<SENSEc, 64, 0, stream>>>(sense_emb, attWk, sk);
    top2_kernel<<<B, 64, 0, stream>>>(pq, sk, out);
}